// Round 17
// baseline (189.282 us; speedup 1.0000x reference)
//
#include <hip/hip_runtime.h>
#include <stdint.h>

#define H 768
#define NHEAD 12
#define HDIM 64
#define BATCH 16
#define TSEQ 512
#define BT (BATCH*TSEQ)      // 8192 tokens
#define C3 (3*H)             // 2304

typedef __attribute__((ext_vector_type(8))) short short8;
typedef __attribute__((ext_vector_type(4))) float floatx4;
typedef unsigned short u16;

__device__ __forceinline__ u16 f2bf(float f) {
    union { float f; unsigned int u; } v; v.f = f;
    unsigned int u = v.u;
    return (u16)((u + 0x7FFFu + ((u >> 16) & 1u)) >> 16);
}

// async global->LDS, 16B per lane; LDS dest = wave-uniform base + lane*16
__device__ __forceinline__ void async_ld16(const void* g, void* l) {
    __builtin_amdgcn_global_load_lds((__attribute__((address_space(1))) void*)g,
                                     (__attribute__((address_space(3))) void*)l,
                                     16, 0, 0);
}

// ---------------------------------------------------------------------------
// Prep (merged): blocks [0,2304): Wall/Wobf/bias (x4 vectorized);
// [2304,8448): x->bf16; [8448,8464): per-batch mask compaction — exp(-1e9)=0
// exactly, so dropping masked keys is semantics-preserving.
// ---------------------------------------------------------------------------
#define PREP_BLOCKS 2304     // 4*H*H/1024 (4 elems/thread)
#define CVT_BLOCKS  6144     // BT*H/1024
#define CMP_BLOCKS  16       // one block (one wave) per batch
__global__ void prep_kernel(const float* __restrict__ Wq, const float* __restrict__ bq,
                            const float* __restrict__ Aq, const float* __restrict__ Bq,
                            const float* __restrict__ Wk, const float* __restrict__ bk,
                            const float* __restrict__ Wv, const float* __restrict__ bv,
                            const float* __restrict__ Av, const float* __restrict__ Bv,
                            const float* __restrict__ Wo, const float* __restrict__ x,
                            const int* __restrict__ mask,
                            u16* __restrict__ Wall, u16* __restrict__ Wobf,
                            float* __restrict__ bias_all, u16* __restrict__ xb,
                            u16* __restrict__ tokl, int* __restrict__ nvalid)
{
    const int bid = blockIdx.x;
    if (bid >= PREP_BLOCKS + CVT_BLOCKS) {
        // mask compaction: wave 0 only; ballot+popcount stable compaction
        const int b = bid - (PREP_BLOCKS + CVT_BLOCKS);
        if (threadIdx.x >= 64) return;
        const int lane = threadIdx.x;
        int base = 0;
        for (int t0 = 0; t0 < TSEQ; t0 += 64) {
            const int mv = mask[b*TSEQ + t0 + lane];
            const unsigned long long bal = __ballot(mv != 0);
            if (mv != 0) {
                const int pre = __popcll(bal & ((1ull << lane) - 1ull));
                tokl[b*TSEQ + base + pre] = (u16)(t0 + lane);
            }
            base += __popcll(bal);
        }
        if (lane == 0) nvalid[b] = base;
        for (int i = base + lane; i < TSEQ; i += 64) tokl[b*TSEQ + i] = 0; // pad -> token 0
        return;
    }
    if (bid >= PREP_BLOCKS) {
        const int i = ((bid - PREP_BLOCKS) * 256 + threadIdx.x) * 4;
        const float4 v = *(const float4*)(x + i);
        u16 o[4] = { f2bf(v.x), f2bf(v.y), f2bf(v.z), f2bf(v.w) };
        *(uint2*)(xb + i) = *(const uint2*)o;
        return;
    }
    // W-fold, 4 elems/thread (H, 2H, 3H, C3 all multiples of 4 -> no straddle)
    const int idx = (bid * 256 + threadIdx.x) * 4;   // < 4*H*H
    const int r = idx / H;
    const int c = idx - r * H;
    u16 o[4];
    if (r < H) {
        const float4 w  = *(const float4*)(Wq + idx);
        const float4 a0 = *(const float4*)(Aq + c);
        const float4 a1 = *(const float4*)(Aq + H + c);
        const float4 a2 = *(const float4*)(Aq + 2*H + c);
        const float4 a3 = *(const float4*)(Aq + 3*H + c);
        const float b0 = Bq[r*4+0], b1 = Bq[r*4+1], b2 = Bq[r*4+2], b3 = Bq[r*4+3];
        o[0] = f2bf(w.x + 2.0f*(b0*a0.x + b1*a1.x + b2*a2.x + b3*a3.x));
        o[1] = f2bf(w.y + 2.0f*(b0*a0.y + b1*a1.y + b2*a2.y + b3*a3.y));
        o[2] = f2bf(w.z + 2.0f*(b0*a0.z + b1*a1.z + b2*a2.z + b3*a3.z));
        o[3] = f2bf(w.w + 2.0f*(b0*a0.w + b1*a1.w + b2*a2.w + b3*a3.w));
        *(uint2*)(Wall + idx) = *(const uint2*)o;
    } else if (r < 2*H) {
        const float4 w = *(const float4*)(Wk + idx - H*H);
        o[0] = f2bf(w.x); o[1] = f2bf(w.y); o[2] = f2bf(w.z); o[3] = f2bf(w.w);
        *(uint2*)(Wall + idx) = *(const uint2*)o;
    } else if (r < 3*H) {
        const int rr = r - 2*H;
        const float4 w  = *(const float4*)(Wv + rr*H + c);
        const float4 a0 = *(const float4*)(Av + c);
        const float4 a1 = *(const float4*)(Av + H + c);
        const float4 a2 = *(const float4*)(Av + 2*H + c);
        const float4 a3 = *(const float4*)(Av + 3*H + c);
        const float b0 = Bv[rr*4+0], b1 = Bv[rr*4+1], b2 = Bv[rr*4+2], b3 = Bv[rr*4+3];
        o[0] = f2bf(w.x + 2.0f*(b0*a0.x + b1*a1.x + b2*a2.x + b3*a3.x));
        o[1] = f2bf(w.y + 2.0f*(b0*a0.y + b1*a1.y + b2*a2.y + b3*a3.y));
        o[2] = f2bf(w.z + 2.0f*(b0*a0.z + b1*a1.z + b2*a2.z + b3*a3.z));
        o[3] = f2bf(w.w + 2.0f*(b0*a0.w + b1*a1.w + b2*a2.w + b3*a3.w));
        *(uint2*)(Wall + idx) = *(const uint2*)o;
    } else {
        const float4 w = *(const float4*)(Wo + idx - 3*H*H);
        o[0] = f2bf(w.x); o[1] = f2bf(w.y); o[2] = f2bf(w.z); o[3] = f2bf(w.w);
        *(uint2*)(Wobf + idx - 3*H*H) = *(const uint2*)o;
    }
    if (idx < C3) {
        #pragma unroll
        for (int j = 0; j < 4; j++) {
            const int i = idx + j;
            bias_all[i] = (i < H) ? bq[i] : (i < 2*H ? bk[i - H] : bv[i - 2*H]);
        }
    }
}

// ---------------------------------------------------------------------------
// GEMM body: C[M][N] = A[M][K] * B[N][K]^T + bias   (A,B bf16, acc fp32)
// Serial BK=64 LDS K-loop — the best of four measured schedules (serial=50.6,
// dbuf64=59.8, dbuf32=53.7, reg-direct=144.8 µs on gemm_qkv). XOR-swizzled
// LDS (0 conflicts), plain epilogue, XCD block remap. TM=128 everywhere
// (m92->m93 tile lever: 2x MFMA per barrier-drain at same 32 KB LDS;
// R15 measured: K-proj 64->128 + out-GEMM 64->128 => qkv 50.6->46.4 on a
// slower chip, total-best 187.4).
// MAP 0: m-comb per XCD, n-major. MAP 1: n-comb per XCD, m fastest.
// MODE 0: fp32 C, per-n bias.  MODE 1: bf16 C, per-n bias.
// MODE 2: transposed-V output vt[bh][d][slot] (m=d_global, n=slot), per-m bias.
// G 0: plain.
// G 1: B rows (n = token slots) gathered via tokl; n-blocks fully past
//      ceil32(nvalid[b]) early-exit (attn never reads those slots).
// G 2: A rows (m = token slots) gathered via tokl; m-blocks fully past
//      ceil32(nvalid[b]) early-exit (K-projection of valid tokens only).
// ---------------------------------------------------------------------------
template<int MODE, int TM, int NB, int MB, int MAP, int G>
__device__ __forceinline__
void gemm_body(const int j, const u16* __restrict__ A, const u16* __restrict__ Bw,
               const float* __restrict__ bias, void* __restrict__ Cout,
               const u16* __restrict__ tokl, const int* __restrict__ nvalid,
               const int K, const int ldc, u16* __restrict__ Ablk, u16* __restrict__ Bblk)
{
    constexpr int MT = TM / 32;            // m-tiles per wave (4 or 2)
    const int tid  = threadIdx.x;
    const int wave = tid >> 6;
    const int lane = tid & 63;
    const int quad = lane >> 4;
    const int l16  = lane & 15;

    int m0, n0;
    {
        const int xcd = j & 7;
        const int loc = j >> 3;
        if (MAP == 0) {
            constexpr int Mx = MB / 8;
            const int dm = loc % Mx;
            const int nb = loc / Mx;
            m0 = (xcd + 8*dm) * TM;
            n0 = nb * 128;
        } else {
            const int dm = loc % MB;
            const int nl = loc / MB;
            m0 = dm * TM;
            n0 = (xcd + 8*nl) * 128;
        }
    }

    if (G == 1) {   // slot n-range fully past what attn reads -> skip
        const int b = n0 >> 9;
        if ((n0 & 511) >= ((nvalid[b] + 31) & ~31)) return;
    }
    if (G == 2) {   // slot m-range fully past what attn reads -> skip
        const int b = m0 >> 9;
        if ((m0 & 511) >= ((nvalid[b] + 31) & ~31)) return;
    }

    const int mw = (wave & 1) * (TM / 2);
    const int nw = (wave >> 1) * 64;

    // staging: wave covers A rows [wave*(TM/4), +TM/4), B rows [wave*32,+32);
    // each async op = 8 rows. lane i -> row r8=i>>3, phys chunk i&7 holds
    // logical chunk (i&7)^r8 (XOR swizzle; conflict-free fragment reads)
    const int r8 = lane >> 3;
    const int kgs = ((lane & 7) ^ r8) * 8;
    const u16* gA = A  + (size_t)(m0 + wave*(TM/4) + r8) * K + kgs;
    const u16* gB = Bw + (size_t)(n0 + wave*32      + r8) * K + kgs;
    const u16* gAp[MT];
    const u16* gBp[4];
    if (G == 2) {
        #pragma unroll
        for (int jj = 0; jj < MT; jj++) {
            const int rs = m0 + wave*(TM/4) + jj*8 + r8;    // global slot
            const int row = (rs & ~511) + (int)tokl[rs];    // gathered token
            gAp[jj] = A + (size_t)row * K + kgs;
        }
    }
    if (G == 1) {
        #pragma unroll
        for (int jj = 0; jj < 4; jj++) {
            const int rb = n0 + wave*32 + jj*8 + r8;        // global slot
            const int row = (rb & ~511) + (int)tokl[rb];    // gathered token
            gBp[jj] = Bw + (size_t)row * K + kgs;
        }
    }
    u16* lA = Ablk + wave * (TM/4) * 64;
    u16* lB = Bblk + wave * 32 * 64;

    floatx4 acc[MT][4] = {};
    const int sw = l16 & 7;    // reader swizzle key (row&7 == l16&7)

    for (int k0 = 0; k0 < K; k0 += 64) {
        __syncthreads();
        #pragma unroll
        for (int jj = 0; jj < MT; jj++) {
            if (G == 2) async_ld16(gAp[jj] + k0, lA + jj*8*64);
            else        async_ld16(gA + k0 + (size_t)(jj*8) * K, lA + jj*8*64);
        }
        #pragma unroll
        for (int jj = 0; jj < 4; jj++) {
            if (G == 1) async_ld16(gBp[jj] + k0, lB + jj*8*64);
            else        async_ld16(gB + k0 + (size_t)(jj*8) * K, lB + jj*8*64);
        }
        __syncthreads();
        #pragma unroll
        for (int kk = 0; kk < 2; kk++) {
            short8 af[MT], bfr[4];
            #pragma unroll
            for (int mt = 0; mt < MT; mt++)
                af[mt] = *(const short8*)(Ablk + (mw + mt*16 + l16)*64 + ((quad + 4*kk) ^ sw)*8);
            #pragma unroll
            for (int nt = 0; nt < 4; nt++)
                bfr[nt] = *(const short8*)(Bblk + (nw + nt*16 + l16)*64 + ((quad + 4*kk) ^ sw)*8);
            #pragma unroll
            for (int mt = 0; mt < MT; mt++)
                #pragma unroll
                for (int nt = 0; nt < 4; nt++)
                    acc[mt][nt] = __builtin_amdgcn_mfma_f32_16x16x32_bf16(af[mt], bfr[nt], acc[mt][nt], 0, 0, 0);
        }
    }

    // epilogue: C layout col=lane&15, row=quad*4+reg
    if (MODE == 2) {
        // vt[bh][d][slot] <- C[m=d_global][n=slot], per-m bias, coalesced in l16
        #pragma unroll
        for (int mt = 0; mt < MT; mt++) {
            #pragma unroll
            for (int r = 0; r < 4; r++) {
                const int m  = m0 + mw + mt*16 + quad*4 + r;
                const float bv = bias[m];
                const int hh = m >> 6, d = m & 63;
                #pragma unroll
                for (int nt = 0; nt < 4; nt++) {
                    const int n = n0 + nw + nt*16 + l16;
                    const int b = n >> 9, t = n & 511;
                    ((u16*)Cout)[((size_t)((b*NHEAD + hh)*HDIM + d))*TSEQ + t]
                        = f2bf(acc[mt][nt][r] + bv);
                }
            }
        }
    } else {
        #pragma unroll
        for (int nt = 0; nt < 4; nt++) {
            const int n = n0 + nw + nt*16 + l16;
            const float bv = bias[n];
            #pragma unroll
            for (int mt = 0; mt < MT; mt++) {
                #pragma unroll
                for (int r = 0; r < 4; r++) {
                    const int m = m0 + mw + mt*16 + quad*4 + r;
                    const float v = acc[mt][nt][r] + bv;
                    if (MODE == 1) ((u16*)Cout)[(size_t)m * ldc + n] = f2bf(v);
                    else           ((float*)Cout)[(size_t)m * ldc + n] = v;
                }
            }
        }
    }
}

template<int MODE, int TM, int NB, int MB, int MAP, int G>
__global__ __launch_bounds__(256)
void gemm_bt(const u16* __restrict__ A, const u16* __restrict__ Bw,
             const float* __restrict__ bias, void* __restrict__ Cout,
             const u16* __restrict__ tokl, const int* __restrict__ nvalid,
             int K, int ldc)
{
    __shared__ u16 Ablk[TM * 64];
    __shared__ u16 Bblk[128 * 64];
    gemm_body<MODE,TM,NB,MB,MAP,G>(blockIdx.x, A, Bw, bias, Cout, tokl, nvalid,
                                   K, ldc, Ablk, Bblk);
}

// ---------------------------------------------------------------------------
// Combined Q/K/V projection launch (independent sub-GEMMs, one dispatch):
//   [0,384):    Q-proj  M=8192 tokens (TM=128), N=768      -> qb[tok][768]
//   [384,768):  K-proj  M=8192 slots, A-gathered (TM=128), -> kc[slot][768]
//               m-blocks past ceil32(nvalid) early-exit (~40% of K flops cut)
//   [768,1152): V-proj  MODE2 TM=128 (MB=6), B-gathered, n-early-exit
//               -> vt[bh][d][slot]
// Segment offsets are multiples of 8 so the &7 XCD decode stays aligned.
// ---------------------------------------------------------------------------
__global__ __launch_bounds__(256)
void gemm_qkv(const u16* __restrict__ xb, const u16* __restrict__ Wall,
              const float* __restrict__ biasall,
              u16* __restrict__ qb, u16* __restrict__ kc, u16* __restrict__ vt,
              const u16* __restrict__ tokl, const int* __restrict__ nvalid)
{
    __shared__ u16 Ablk[128 * 64];
    __shared__ u16 Bblk[128 * 64];
    const int bid = blockIdx.x;
    if (bid < 384) {
        gemm_body<1,128,6,64,0,0>(bid, xb, Wall, biasall, qb,
                                  nullptr, nullptr, H, H, Ablk, Bblk);
    } else if (bid < 768) {
        gemm_body<1,128,6,64,0,2>(bid - 384, xb, Wall + (size_t)H*H, biasall + H, kc,
                                  tokl, nvalid, H, H, Ablk, Bblk);
    } else {
        gemm_body<2,128,64,6,1,1>(bid - 768, Wall + (size_t)2*H*H, xb, biasall + 2*H, vt,
                                  tokl, nvalid, H, 0, Ablk, Bblk);
    }
}

// ---------------------------------------------------------------------------
// Attention over COMPACTED keys: iterates ceil(nvalid/32) tiles (~8-9 of 16).
// K read CONTIGUOUSLY from slot-compacted kc; V^T already slot-compacted by
// the V GEMM. Masked keys contribute exactly 0 (exp(-1e9)=0), so compaction
// is semantics-preserving.
// ---------------------------------------------------------------------------
#define PSTRIDE 40   // u16; 80 B rows: conflict-free writes + b128 reads

__global__ __launch_bounds__(256)
void attn_kernel(const u16* __restrict__ qb, const u16* __restrict__ kc,
                 const u16* __restrict__ vt, const int* __restrict__ nvalid,
                 u16* __restrict__ attn_out)
{
    __shared__ float maskadd[TSEQ];                 // 2 KB (slot-domain pad mask)
    __shared__ u16 Kbuf[2][32 * 64];                // 8 KB  [key][d], swizzled
    __shared__ u16 Vbuf[2][64 * 32];                // 8 KB  [d][key], swizzled
    __shared__ u16 Pbuf[4][2][16 * PSTRIDE];        // 10 KB

    const int qt = blockIdx.x;        // 0..3 (128 q rows per block)
    const int bh = blockIdx.y;        // 0..191
    const int b = bh / NHEAD, h = bh - b * NHEAD;
    const int tid  = threadIdx.x;
    const int wave = tid >> 6;
    const int lane = tid & 63;
    const int quad = lane >> 4;
    const int l16  = lane & 15;

    const int nv = nvalid[b];
    const int nt = (nv + 31) >> 5;    // key tiles of 32 (uniform per block)

    for (int i = tid; i < TSEQ; i += 256)
        maskadd[i] = (i < nv) ? 0.0f : -1e9f;

    const size_t btok = (size_t)b * TSEQ;
    const int q0 = qt * 128 + wave * 32;

    // Q fragments for 2 row-tiles: A[m=l16][k=quad*8+j], two d-halves
    short8 qf[2][2];
    #pragma unroll
    for (int m = 0; m < 2; m++) {
        const u16* qp = qb + (btok + q0 + m*16 + l16) * H + h*HDIM + quad*8;
        qf[m][0] = *(const short8*)qp;
        qf[m][1] = *(const short8*)(qp + 32);
    }

    const u16* kglob = kc + btok * H + h*HDIM;          // compacted K rows, stride H
    const u16* vglob = vt + (size_t)bh * HDIM * TSEQ;   // V^T rows, stride TSEQ

    auto stage = [&](int kb, int pp) {
        {   // K[slot][d]: lane i -> slot kb+w*8+(i>>3), phys chunk i&7 = logical ^ (slot&7)
            const int r = lane >> 3;
            const int g = (lane & 7) ^ r;
            async_ld16(kglob + (size_t)(kb + wave*8 + r) * H + g*8,
                       &Kbuf[pp][wave*8*64]);
        }
        {   // V^T[d][key]: lane i -> d w*16+(i>>2), phys chunk i&3 = logical ^ ((d>>1)&3)
            const int dr = lane >> 2;
            const int g  = (lane & 3) ^ ((dr >> 1) & 3);
            async_ld16(vglob + (size_t)(wave*16 + dr) * TSEQ + kb + g*8,
                       &Vbuf[pp][wave*16*32]);
        }
    };

    floatx4 o[2][4] = {};              // 2 x (16q x 64d), C-layout
    float lsum[2][4] = {};

    auto compute = [&](int kb, int pp) {
        const u16* Kb_ = Kbuf[pp];
        const u16* Vb_ = Vbuf[pp];
        short8 kf[2][2];
        #pragma unroll
        for (int t = 0; t < 2; t++)
            #pragma unroll
            for (int h2 = 0; h2 < 2; h2++)
                kf[t][h2] = *(const short8*)(Kb_ + (t*16 + l16)*64 + (((h2*4 + quad) ^ (l16 & 7))*8));
        short8 vf[4];
        #pragma unroll
        for (int dt = 0; dt < 4; dt++)
            vf[dt] = *(const short8*)(Vb_ + (dt*16 + l16)*32 + ((quad ^ ((l16 >> 1) & 3))*8));

        floatx4 s[2][2];
        #pragma unroll
        for (int m = 0; m < 2; m++)
            #pragma unroll
            for (int t = 0; t < 2; t++) {
                floatx4 acc = {0.f, 0.f, 0.f, 0.f};
                acc = __builtin_amdgcn_mfma_f32_16x16x32_bf16(qf[m][0], kf[t][0], acc, 0, 0, 0);
                acc = __builtin_amdgcn_mfma_f32_16x16x32_bf16(qf[m][1], kf[t][1], acc, 0, 0, 0);
                s[m][t] = acc;
            }
        const float m0 = maskadd[kb + l16];
        const float m1 = maskadd[kb + 16 + l16];
        #pragma unroll
        for (int m = 0; m < 2; m++) {
            u16* Pw = Pbuf[wave][m];
            #pragma unroll
            for (int r = 0; r < 4; r++) {
                const float p0 = __expf(s[m][0][r] * 0.125f + m0);
                const float p1 = __expf(s[m][1][r] * 0.125f + m1);
                lsum[m][r] += p0 + p1;
                Pw[(quad*4 + r) * PSTRIDE + l16]      = f2bf(p0);
                Pw[(quad*4 + r) * PSTRIDE + 16 + l16] = f2bf(p1);
            }
        }
        #pragma unroll
        for (int m = 0; m < 2; m++) {
            const short8 pa = *(const short8*)(Pbuf[wave][m] + l16 * PSTRIDE + quad*8);
            #pragma unroll
            for (int dt = 0; dt < 4; dt++)
                o[m][dt] = __builtin_amdgcn_mfma_f32_16x16x32_bf16(pa, vf[dt], o[m][dt], 0, 0, 0);
        }
    };

    stage(0, 0);
    for (int it = 0; it < nt; it++) {
        __syncthreads();
        if (it < nt - 1) stage((it + 1) * 32, (it + 1) & 1);
        compute(it * 32, it & 1);
    }

    #pragma unroll
    for (int m = 0; m < 2; m++) {
        float inv[4];
        #pragma unroll
        for (int r = 0; r < 4; r++) {
            float l = lsum[m][r];
            l += __shfl_xor(l, 1);
            l += __shfl_xor(l, 2);
            l += __shfl_xor(l, 4);
            l += __shfl_xor(l, 8);
            inv[r] = 1.0f / l;
        }
        #pragma unroll
        for (int dt = 0; dt < 4; dt++)
            #pragma unroll
            for (int r = 0; r < 4; r++) {
                const int q = q0 + m*16 + quad*4 + r;
                attn_out[(btok + q) * H + h*HDIM + dt*16 + l16] = f2bf(o[m][dt][r] * inv[r]);
            }
    }
}

// ---------------------------------------------------------------------------
extern "C" void kernel_launch(void* const* d_in, const int* in_sizes, int n_in,
                              void* d_out, int out_size, void* d_ws, size_t ws_size,
                              hipStream_t stream)
{
    const float* x   = (const float*)d_in[0];
    const int* mask  = (const int*)d_in[1];
    const float* Wq  = (const float*)d_in[2];
    const float* bq  = (const float*)d_in[3];
    const float* Aq  = (const float*)d_in[4];
    const float* Bq  = (const float*)d_in[5];
    const float* Wk  = (const float*)d_in[6];
    const float* bk  = (const float*)d_in[7];
    const float* Wv  = (const float*)d_in[8];
    const float* bv  = (const float*)d_in[9];
    const float* Av  = (const float*)d_in[10];
    const float* Bv  = (const float*)d_in[11];
    const float* Wo  = (const float*)d_in[12];
    const float* bo  = (const float*)d_in[13];

    char* ws = (char*)d_ws;
    u16*   xb      = (u16*)  (ws);                 // 12,582,912 B
    u16*   Wall    = (u16*)  (ws + 12582912);      //  3,538,944 B
    u16*   Wobf    = (u16*)  (ws + 16121856);      //  1,179,648 B
    float* biasall = (float*)(ws + 17301504);      //      9,216 B
    u16*   qb      = (u16*)  (ws + 17310720);      // 12,582,912 B
    u16*   kc      = (u16*)  (ws + 29893632);      // 12,582,912 B
    u16*   vt      = (u16*)  (ws + 42476544);      // 12,582,912 B
    u16*   attn_o  = (u16*)  (ws + 55059456);      // 12,582,912 B (end 67,642,368)

    // compaction scratch lives in the TAIL of d_out: it is consumed by
    // QKV-GEMM + attn, and only afterwards does the out-GEMM overwrite all of
    // d_out. Zero workspace growth.
    int* nvalid = (int*)((char*)d_out + 25149376); //     64 B
    u16* tokl   = (u16*)((char*)d_out + 25149440); // 16,384 B (end 25,165,824)

    prep_kernel<<<PREP_BLOCKS + CVT_BLOCKS + CMP_BLOCKS, 256, 0, stream>>>(
        Wq, bq, Aq, Bq, Wk, bk, Wv, bv, Av, Bv, Wo, x, mask,
        Wall, Wobf, biasall, xb, tokl, nvalid);
    // Q-proj + compacted K-proj + compacted V-proj (all TM=128), one dispatch
    gemm_qkv<<<1152, 256, 0, stream>>>(xb, Wall, biasall, qb, kc, vt, tokl, nvalid);
    attn_kernel<<<dim3(TSEQ/128, BATCH*NHEAD), 256, 0, stream>>>(qb, kc, vt, nvalid, attn_o);
    // Output GEMM: M=8192 (64 blocks of TM=128), N=768 (6 n-blocks), MAP0
    gemm_bt<0,128,6,64,0,0><<<6*64, 256, 0, stream>>>(attn_o, Wobf, bo, d_out,
                                                      nullptr, nullptr, H, H);
}

// Round 18
// 186.877 us; speedup vs baseline: 1.0129x; 1.0129x over previous
//
#include <hip/hip_runtime.h>
#include <stdint.h>

#define H 768
#define NHEAD 12
#define HDIM 64
#define BATCH 16
#define TSEQ 512
#define BT (BATCH*TSEQ)      // 8192 tokens
#define C3 (3*H)             // 2304

typedef __attribute__((ext_vector_type(8))) short short8;
typedef __attribute__((ext_vector_type(4))) float floatx4;
typedef unsigned short u16;

__device__ __forceinline__ u16 f2bf(float f) {
    union { float f; unsigned int u; } v; v.f = f;
    unsigned int u = v.u;
    return (u16)((u + 0x7FFFu + ((u >> 16) & 1u)) >> 16);
}

// async global->LDS, 16B per lane; LDS dest = wave-uniform base + lane*16
__device__ __forceinline__ void async_ld16(const void* g, void* l) {
    __builtin_amdgcn_global_load_lds((__attribute__((address_space(1))) void*)g,
                                     (__attribute__((address_space(3))) void*)l,
                                     16, 0, 0);
}

// ---------------------------------------------------------------------------
// Prep (merged): blocks [0,2304): Wall/Wobf/bias (x4 vectorized);
// [2304,8448): x->bf16; [8448,8464): per-batch mask compaction — exp(-1e9)=0
// exactly, so dropping masked keys is semantics-preserving.
// ---------------------------------------------------------------------------
#define PREP_BLOCKS 2304     // 4*H*H/1024 (4 elems/thread)
#define CVT_BLOCKS  6144     // BT*H/1024
#define CMP_BLOCKS  16       // one block (one wave) per batch
__global__ void prep_kernel(const float* __restrict__ Wq, const float* __restrict__ bq,
                            const float* __restrict__ Aq, const float* __restrict__ Bq,
                            const float* __restrict__ Wk, const float* __restrict__ bk,
                            const float* __restrict__ Wv, const float* __restrict__ bv,
                            const float* __restrict__ Av, const float* __restrict__ Bv,
                            const float* __restrict__ Wo, const float* __restrict__ x,
                            const int* __restrict__ mask,
                            u16* __restrict__ Wall, u16* __restrict__ Wobf,
                            float* __restrict__ bias_all, u16* __restrict__ xb,
                            u16* __restrict__ tokl, int* __restrict__ nvalid)
{
    const int bid = blockIdx.x;
    if (bid >= PREP_BLOCKS + CVT_BLOCKS) {
        // mask compaction: wave 0 only; ballot+popcount stable compaction
        const int b = bid - (PREP_BLOCKS + CVT_BLOCKS);
        if (threadIdx.x >= 64) return;
        const int lane = threadIdx.x;
        int base = 0;
        for (int t0 = 0; t0 < TSEQ; t0 += 64) {
            const int mv = mask[b*TSEQ + t0 + lane];
            const unsigned long long bal = __ballot(mv != 0);
            if (mv != 0) {
                const int pre = __popcll(bal & ((1ull << lane) - 1ull));
                tokl[b*TSEQ + base + pre] = (u16)(t0 + lane);
            }
            base += __popcll(bal);
        }
        if (lane == 0) nvalid[b] = base;
        for (int i = base + lane; i < TSEQ; i += 64) tokl[b*TSEQ + i] = 0; // pad -> token 0
        return;
    }
    if (bid >= PREP_BLOCKS) {
        const int i = ((bid - PREP_BLOCKS) * 256 + threadIdx.x) * 4;
        const float4 v = *(const float4*)(x + i);
        u16 o[4] = { f2bf(v.x), f2bf(v.y), f2bf(v.z), f2bf(v.w) };
        *(uint2*)(xb + i) = *(const uint2*)o;
        return;
    }
    // W-fold, 4 elems/thread (H, 2H, 3H, C3 all multiples of 4 -> no straddle)
    const int idx = (bid * 256 + threadIdx.x) * 4;   // < 4*H*H
    const int r = idx / H;
    const int c = idx - r * H;
    u16 o[4];
    if (r < H) {
        const float4 w  = *(const float4*)(Wq + idx);
        const float4 a0 = *(const float4*)(Aq + c);
        const float4 a1 = *(const float4*)(Aq + H + c);
        const float4 a2 = *(const float4*)(Aq + 2*H + c);
        const float4 a3 = *(const float4*)(Aq + 3*H + c);
        const float b0 = Bq[r*4+0], b1 = Bq[r*4+1], b2 = Bq[r*4+2], b3 = Bq[r*4+3];
        o[0] = f2bf(w.x + 2.0f*(b0*a0.x + b1*a1.x + b2*a2.x + b3*a3.x));
        o[1] = f2bf(w.y + 2.0f*(b0*a0.y + b1*a1.y + b2*a2.y + b3*a3.y));
        o[2] = f2bf(w.z + 2.0f*(b0*a0.z + b1*a1.z + b2*a2.z + b3*a3.z));
        o[3] = f2bf(w.w + 2.0f*(b0*a0.w + b1*a1.w + b2*a2.w + b3*a3.w));
        *(uint2*)(Wall + idx) = *(const uint2*)o;
    } else if (r < 2*H) {
        const float4 w = *(const float4*)(Wk + idx - H*H);
        o[0] = f2bf(w.x); o[1] = f2bf(w.y); o[2] = f2bf(w.z); o[3] = f2bf(w.w);
        *(uint2*)(Wall + idx) = *(const uint2*)o;
    } else if (r < 3*H) {
        const int rr = r - 2*H;
        const float4 w  = *(const float4*)(Wv + rr*H + c);
        const float4 a0 = *(const float4*)(Av + c);
        const float4 a1 = *(const float4*)(Av + H + c);
        const float4 a2 = *(const float4*)(Av + 2*H + c);
        const float4 a3 = *(const float4*)(Av + 3*H + c);
        const float b0 = Bv[rr*4+0], b1 = Bv[rr*4+1], b2 = Bv[rr*4+2], b3 = Bv[rr*4+3];
        o[0] = f2bf(w.x + 2.0f*(b0*a0.x + b1*a1.x + b2*a2.x + b3*a3.x));
        o[1] = f2bf(w.y + 2.0f*(b0*a0.y + b1*a1.y + b2*a2.y + b3*a3.y));
        o[2] = f2bf(w.z + 2.0f*(b0*a0.z + b1*a1.z + b2*a2.z + b3*a3.z));
        o[3] = f2bf(w.w + 2.0f*(b0*a0.w + b1*a1.w + b2*a2.w + b3*a3.w));
        *(uint2*)(Wall + idx) = *(const uint2*)o;
    } else {
        const float4 w = *(const float4*)(Wo + idx - 3*H*H);
        o[0] = f2bf(w.x); o[1] = f2bf(w.y); o[2] = f2bf(w.z); o[3] = f2bf(w.w);
        *(uint2*)(Wobf + idx - 3*H*H) = *(const uint2*)o;
    }
    if (idx < C3) {
        #pragma unroll
        for (int j = 0; j < 4; j++) {
            const int i = idx + j;
            bias_all[i] = (i < H) ? bq[i] : (i < 2*H ? bk[i - H] : bv[i - 2*H]);
        }
    }
}

// ---------------------------------------------------------------------------
// GEMM body: C[M][N] = A[M][K] * B[N][K]^T + bias   (A,B bf16, acc fp32)
// Serial BK=64 LDS K-loop — the best of four measured schedules (serial=50.6,
// dbuf64=59.8, dbuf32=53.7, reg-direct=144.8 µs on gemm_qkv). XOR-swizzled
// LDS (0 conflicts), plain epilogue, XCD block remap.
// Tile sizes per segment are MEASURED choices: Q/K-proj + out-GEMM TM=128
// (R15 win); V-proj TM=64 (R17: TM=128 dropped occupancy 13.4->11.2 and was
// neutral-to-negative — grid under-fills the 5-blocks/CU capacity).
// MAP 0: m-comb per XCD, n-major. MAP 1: n-comb per XCD, m fastest.
// MODE 0: fp32 C, per-n bias.  MODE 1: bf16 C, per-n bias.
// MODE 2: transposed-V output vt[bh][d][slot] (m=d_global, n=slot), per-m bias.
// G 0: plain.
// G 1: B rows (n = token slots) gathered via tokl; n-blocks fully past
//      ceil32(nvalid[b]) early-exit (attn never reads those slots).
// G 2: A rows (m = token slots) gathered via tokl; m-blocks fully past
//      ceil32(nvalid[b]) early-exit (K-projection of valid tokens only).
// ---------------------------------------------------------------------------
template<int MODE, int TM, int NB, int MB, int MAP, int G>
__device__ __forceinline__
void gemm_body(const int j, const u16* __restrict__ A, const u16* __restrict__ Bw,
               const float* __restrict__ bias, void* __restrict__ Cout,
               const u16* __restrict__ tokl, const int* __restrict__ nvalid,
               const int K, const int ldc, u16* __restrict__ Ablk, u16* __restrict__ Bblk)
{
    constexpr int MT = TM / 32;            // m-tiles per wave (4 or 2)
    const int tid  = threadIdx.x;
    const int wave = tid >> 6;
    const int lane = tid & 63;
    const int quad = lane >> 4;
    const int l16  = lane & 15;

    int m0, n0;
    {
        const int xcd = j & 7;
        const int loc = j >> 3;
        if (MAP == 0) {
            constexpr int Mx = MB / 8;
            const int dm = loc % Mx;
            const int nb = loc / Mx;
            m0 = (xcd + 8*dm) * TM;
            n0 = nb * 128;
        } else {
            const int dm = loc % MB;
            const int nl = loc / MB;
            m0 = dm * TM;
            n0 = (xcd + 8*nl) * 128;
        }
    }

    if (G == 1) {   // slot n-range fully past what attn reads -> skip
        const int b = n0 >> 9;
        if ((n0 & 511) >= ((nvalid[b] + 31) & ~31)) return;
    }
    if (G == 2) {   // slot m-range fully past what attn reads -> skip
        const int b = m0 >> 9;
        if ((m0 & 511) >= ((nvalid[b] + 31) & ~31)) return;
    }

    const int mw = (wave & 1) * (TM / 2);
    const int nw = (wave >> 1) * 64;

    // staging: wave covers A rows [wave*(TM/4), +TM/4), B rows [wave*32,+32);
    // each async op = 8 rows. lane i -> row r8=i>>3, phys chunk i&7 holds
    // logical chunk (i&7)^r8 (XOR swizzle; conflict-free fragment reads)
    const int r8 = lane >> 3;
    const int kgs = ((lane & 7) ^ r8) * 8;
    const u16* gA = A  + (size_t)(m0 + wave*(TM/4) + r8) * K + kgs;
    const u16* gB = Bw + (size_t)(n0 + wave*32      + r8) * K + kgs;
    const u16* gAp[MT];
    const u16* gBp[4];
    if (G == 2) {
        #pragma unroll
        for (int jj = 0; jj < MT; jj++) {
            const int rs = m0 + wave*(TM/4) + jj*8 + r8;    // global slot
            const int row = (rs & ~511) + (int)tokl[rs];    // gathered token
            gAp[jj] = A + (size_t)row * K + kgs;
        }
    }
    if (G == 1) {
        #pragma unroll
        for (int jj = 0; jj < 4; jj++) {
            const int rb = n0 + wave*32 + jj*8 + r8;        // global slot
            const int row = (rb & ~511) + (int)tokl[rb];    // gathered token
            gBp[jj] = Bw + (size_t)row * K + kgs;
        }
    }
    u16* lA = Ablk + wave * (TM/4) * 64;
    u16* lB = Bblk + wave * 32 * 64;

    floatx4 acc[MT][4] = {};
    const int sw = l16 & 7;    // reader swizzle key (row&7 == l16&7)

    for (int k0 = 0; k0 < K; k0 += 64) {
        __syncthreads();
        #pragma unroll
        for (int jj = 0; jj < MT; jj++) {
            if (G == 2) async_ld16(gAp[jj] + k0, lA + jj*8*64);
            else        async_ld16(gA + k0 + (size_t)(jj*8) * K, lA + jj*8*64);
        }
        #pragma unroll
        for (int jj = 0; jj < 4; jj++) {
            if (G == 1) async_ld16(gBp[jj] + k0, lB + jj*8*64);
            else        async_ld16(gB + k0 + (size_t)(jj*8) * K, lB + jj*8*64);
        }
        __syncthreads();
        #pragma unroll
        for (int kk = 0; kk < 2; kk++) {
            short8 af[MT], bfr[4];
            #pragma unroll
            for (int mt = 0; mt < MT; mt++)
                af[mt] = *(const short8*)(Ablk + (mw + mt*16 + l16)*64 + ((quad + 4*kk) ^ sw)*8);
            #pragma unroll
            for (int nt = 0; nt < 4; nt++)
                bfr[nt] = *(const short8*)(Bblk + (nw + nt*16 + l16)*64 + ((quad + 4*kk) ^ sw)*8);
            #pragma unroll
            for (int mt = 0; mt < MT; mt++)
                #pragma unroll
                for (int nt = 0; nt < 4; nt++)
                    acc[mt][nt] = __builtin_amdgcn_mfma_f32_16x16x32_bf16(af[mt], bfr[nt], acc[mt][nt], 0, 0, 0);
        }
    }

    // epilogue: C layout col=lane&15, row=quad*4+reg
    if (MODE == 2) {
        // vt[bh][d][slot] <- C[m=d_global][n=slot], per-m bias, coalesced in l16
        #pragma unroll
        for (int mt = 0; mt < MT; mt++) {
            #pragma unroll
            for (int r = 0; r < 4; r++) {
                const int m  = m0 + mw + mt*16 + quad*4 + r;
                const float bv = bias[m];
                const int hh = m >> 6, d = m & 63;
                #pragma unroll
                for (int nt = 0; nt < 4; nt++) {
                    const int n = n0 + nw + nt*16 + l16;
                    const int b = n >> 9, t = n & 511;
                    ((u16*)Cout)[((size_t)((b*NHEAD + hh)*HDIM + d))*TSEQ + t]
                        = f2bf(acc[mt][nt][r] + bv);
                }
            }
        }
    } else {
        #pragma unroll
        for (int nt = 0; nt < 4; nt++) {
            const int n = n0 + nw + nt*16 + l16;
            const float bv = bias[n];
            #pragma unroll
            for (int mt = 0; mt < MT; mt++) {
                #pragma unroll
                for (int r = 0; r < 4; r++) {
                    const int m = m0 + mw + mt*16 + quad*4 + r;
                    const float v = acc[mt][nt][r] + bv;
                    if (MODE == 1) ((u16*)Cout)[(size_t)m * ldc + n] = f2bf(v);
                    else           ((float*)Cout)[(size_t)m * ldc + n] = v;
                }
            }
        }
    }
}

template<int MODE, int TM, int NB, int MB, int MAP, int G>
__global__ __launch_bounds__(256)
void gemm_bt(const u16* __restrict__ A, const u16* __restrict__ Bw,
             const float* __restrict__ bias, void* __restrict__ Cout,
             const u16* __restrict__ tokl, const int* __restrict__ nvalid,
             int K, int ldc)
{
    __shared__ u16 Ablk[TM * 64];
    __shared__ u16 Bblk[128 * 64];
    gemm_body<MODE,TM,NB,MB,MAP,G>(blockIdx.x, A, Bw, bias, Cout, tokl, nvalid,
                                   K, ldc, Ablk, Bblk);
}

// ---------------------------------------------------------------------------
// Combined Q/K/V projection launch (independent sub-GEMMs, one dispatch):
//   [0,384):    Q-proj  M=8192 tokens (TM=128), N=768      -> qb[tok][768]
//   [384,768):  K-proj  M=8192 slots, A-gathered (TM=128), -> kc[slot][768]
//               m-blocks past ceil32(nvalid) early-exit (~40% of K flops cut)
//   [768,1536): V-proj  MODE2 TM=64, B-gathered, n-early-exit -> vt[bh][d][slot]
// Segment offsets are multiples of 8 so the &7 XCD decode stays aligned.
// ---------------------------------------------------------------------------
__global__ __launch_bounds__(256)
void gemm_qkv(const u16* __restrict__ xb, const u16* __restrict__ Wall,
              const float* __restrict__ biasall,
              u16* __restrict__ qb, u16* __restrict__ kc, u16* __restrict__ vt,
              const u16* __restrict__ tokl, const int* __restrict__ nvalid)
{
    __shared__ u16 Ablk[128 * 64];
    __shared__ u16 Bblk[128 * 64];
    const int bid = blockIdx.x;
    if (bid < 384) {
        gemm_body<1,128,6,64,0,0>(bid, xb, Wall, biasall, qb,
                                  nullptr, nullptr, H, H, Ablk, Bblk);
    } else if (bid < 768) {
        gemm_body<1,128,6,64,0,2>(bid - 384, xb, Wall + (size_t)H*H, biasall + H, kc,
                                  tokl, nvalid, H, H, Ablk, Bblk);
    } else {
        gemm_body<2,64,64,12,1,1>(bid - 768, Wall + (size_t)2*H*H, xb, biasall + 2*H, vt,
                                  tokl, nvalid, H, 0, Ablk, Bblk);
    }
}

// ---------------------------------------------------------------------------
// Attention over COMPACTED keys: iterates ceil(nvalid/32) tiles (~8-9 of 16).
// K read CONTIGUOUSLY from slot-compacted kc; V^T already slot-compacted by
// the V GEMM. Masked keys contribute exactly 0 (exp(-1e9)=0), so compaction
// is semantics-preserving.
// ---------------------------------------------------------------------------
#define PSTRIDE 40   // u16; 80 B rows: conflict-free writes + b128 reads

__global__ __launch_bounds__(256)
void attn_kernel(const u16* __restrict__ qb, const u16* __restrict__ kc,
                 const u16* __restrict__ vt, const int* __restrict__ nvalid,
                 u16* __restrict__ attn_out)
{
    __shared__ float maskadd[TSEQ];                 // 2 KB (slot-domain pad mask)
    __shared__ u16 Kbuf[2][32 * 64];                // 8 KB  [key][d], swizzled
    __shared__ u16 Vbuf[2][64 * 32];                // 8 KB  [d][key], swizzled
    __shared__ u16 Pbuf[4][2][16 * PSTRIDE];        // 10 KB

    const int qt = blockIdx.x;        // 0..3 (128 q rows per block)
    const int bh = blockIdx.y;        // 0..191
    const int b = bh / NHEAD, h = bh - b * NHEAD;
    const int tid  = threadIdx.x;
    const int wave = tid >> 6;
    const int lane = tid & 63;
    const int quad = lane >> 4;
    const int l16  = lane & 15;

    const int nv = nvalid[b];
    const int nt = (nv + 31) >> 5;    // key tiles of 32 (uniform per block)

    for (int i = tid; i < TSEQ; i += 256)
        maskadd[i] = (i < nv) ? 0.0f : -1e9f;

    const size_t btok = (size_t)b * TSEQ;
    const int q0 = qt * 128 + wave * 32;

    // Q fragments for 2 row-tiles: A[m=l16][k=quad*8+j], two d-halves
    short8 qf[2][2];
    #pragma unroll
    for (int m = 0; m < 2; m++) {
        const u16* qp = qb + (btok + q0 + m*16 + l16) * H + h*HDIM + quad*8;
        qf[m][0] = *(const short8*)qp;
        qf[m][1] = *(const short8*)(qp + 32);
    }

    const u16* kglob = kc + btok * H + h*HDIM;          // compacted K rows, stride H
    const u16* vglob = vt + (size_t)bh * HDIM * TSEQ;   // V^T rows, stride TSEQ

    auto stage = [&](int kb, int pp) {
        {   // K[slot][d]: lane i -> slot kb+w*8+(i>>3), phys chunk i&7 = logical ^ (slot&7)
            const int r = lane >> 3;
            const int g = (lane & 7) ^ r;
            async_ld16(kglob + (size_t)(kb + wave*8 + r) * H + g*8,
                       &Kbuf[pp][wave*8*64]);
        }
        {   // V^T[d][key]: lane i -> d w*16+(i>>2), phys chunk i&3 = logical ^ ((d>>1)&3)
            const int dr = lane >> 2;
            const int g  = (lane & 3) ^ ((dr >> 1) & 3);
            async_ld16(vglob + (size_t)(wave*16 + dr) * TSEQ + kb + g*8,
                       &Vbuf[pp][wave*16*32]);
        }
    };

    floatx4 o[2][4] = {};              // 2 x (16q x 64d), C-layout
    float lsum[2][4] = {};

    auto compute = [&](int kb, int pp) {
        const u16* Kb_ = Kbuf[pp];
        const u16* Vb_ = Vbuf[pp];
        short8 kf[2][2];
        #pragma unroll
        for (int t = 0; t < 2; t++)
            #pragma unroll
            for (int h2 = 0; h2 < 2; h2++)
                kf[t][h2] = *(const short8*)(Kb_ + (t*16 + l16)*64 + (((h2*4 + quad) ^ (l16 & 7))*8));
        short8 vf[4];
        #pragma unroll
        for (int dt = 0; dt < 4; dt++)
            vf[dt] = *(const short8*)(Vb_ + (dt*16 + l16)*32 + ((quad ^ ((l16 >> 1) & 3))*8));

        floatx4 s[2][2];
        #pragma unroll
        for (int m = 0; m < 2; m++)
            #pragma unroll
            for (int t = 0; t < 2; t++) {
                floatx4 acc = {0.f, 0.f, 0.f, 0.f};
                acc = __builtin_amdgcn_mfma_f32_16x16x32_bf16(qf[m][0], kf[t][0], acc, 0, 0, 0);
                acc = __builtin_amdgcn_mfma_f32_16x16x32_bf16(qf[m][1], kf[t][1], acc, 0, 0, 0);
                s[m][t] = acc;
            }
        const float m0 = maskadd[kb + l16];
        const float m1 = maskadd[kb + 16 + l16];
        #pragma unroll
        for (int m = 0; m < 2; m++) {
            u16* Pw = Pbuf[wave][m];
            #pragma unroll
            for (int r = 0; r < 4; r++) {
                const float p0 = __expf(s[m][0][r] * 0.125f + m0);
                const float p1 = __expf(s[m][1][r] * 0.125f + m1);
                lsum[m][r] += p0 + p1;
                Pw[(quad*4 + r) * PSTRIDE + l16]      = f2bf(p0);
                Pw[(quad*4 + r) * PSTRIDE + 16 + l16] = f2bf(p1);
            }
        }
        #pragma unroll
        for (int m = 0; m < 2; m++) {
            const short8 pa = *(const short8*)(Pbuf[wave][m] + l16 * PSTRIDE + quad*8);
            #pragma unroll
            for (int dt = 0; dt < 4; dt++)
                o[m][dt] = __builtin_amdgcn_mfma_f32_16x16x32_bf16(pa, vf[dt], o[m][dt], 0, 0, 0);
        }
    };

    stage(0, 0);
    for (int it = 0; it < nt; it++) {
        __syncthreads();
        if (it < nt - 1) stage((it + 1) * 32, (it + 1) & 1);
        compute(it * 32, it & 1);
    }

    #pragma unroll
    for (int m = 0; m < 2; m++) {
        float inv[4];
        #pragma unroll
        for (int r = 0; r < 4; r++) {
            float l = lsum[m][r];
            l += __shfl_xor(l, 1);
            l += __shfl_xor(l, 2);
            l += __shfl_xor(l, 4);
            l += __shfl_xor(l, 8);
            inv[r] = 1.0f / l;
        }
        #pragma unroll
        for (int dt = 0; dt < 4; dt++)
            #pragma unroll
            for (int r = 0; r < 4; r++) {
                const int q = q0 + m*16 + quad*4 + r;
                attn_out[(btok + q) * H + h*HDIM + dt*16 + l16] = f2bf(o[m][dt][r] * inv[r]);
            }
    }
}

// ---------------------------------------------------------------------------
extern "C" void kernel_launch(void* const* d_in, const int* in_sizes, int n_in,
                              void* d_out, int out_size, void* d_ws, size_t ws_size,
                              hipStream_t stream)
{
    const float* x   = (const float*)d_in[0];
    const int* mask  = (const int*)d_in[1];
    const float* Wq  = (const float*)d_in[2];
    const float* bq  = (const float*)d_in[3];
    const float* Aq  = (const float*)d_in[4];
    const float* Bq  = (const float*)d_in[5];
    const float* Wk  = (const float*)d_in[6];
    const float* bk  = (const float*)d_in[7];
    const float* Wv  = (const float*)d_in[8];
    const float* bv  = (const float*)d_in[9];
    const float* Av  = (const float*)d_in[10];
    const float* Bv  = (const float*)d_in[11];
    const float* Wo  = (const float*)d_in[12];
    const float* bo  = (const float*)d_in[13];

    char* ws = (char*)d_ws;
    u16*   xb      = (u16*)  (ws);                 // 12,582,912 B
    u16*   Wall    = (u16*)  (ws + 12582912);      //  3,538,944 B
    u16*   Wobf    = (u16*)  (ws + 16121856);      //  1,179,648 B
    float* biasall = (float*)(ws + 17301504);      //      9,216 B
    u16*   qb      = (u16*)  (ws + 17310720);      // 12,582,912 B
    u16*   kc      = (u16*)  (ws + 29893632);      // 12,582,912 B
    u16*   vt      = (u16*)  (ws + 42476544);      // 12,582,912 B
    u16*   attn_o  = (u16*)  (ws + 55059456);      // 12,582,912 B (end 67,642,368)

    // compaction scratch lives in the TAIL of d_out: it is consumed by
    // QKV-GEMM + attn, and only afterwards does the out-GEMM overwrite all of
    // d_out. Zero workspace growth.
    int* nvalid = (int*)((char*)d_out + 25149376); //     64 B
    u16* tokl   = (u16*)((char*)d_out + 25149440); // 16,384 B (end 25,165,824)

    prep_kernel<<<PREP_BLOCKS + CVT_BLOCKS + CMP_BLOCKS, 256, 0, stream>>>(
        Wq, bq, Aq, Bq, Wk, bk, Wv, bv, Av, Bv, Wo, x, mask,
        Wall, Wobf, biasall, xb, tokl, nvalid);
    // Q-proj + compacted K-proj (TM=128) + compacted V-proj (TM=64), one dispatch
    gemm_qkv<<<1536, 256, 0, stream>>>(xb, Wall, biasall, qb, kc, vt, tokl, nvalid);
    attn_kernel<<<dim3(TSEQ/128, BATCH*NHEAD), 256, 0, stream>>>(qb, kc, vt, nvalid, attn_o);
    // Output GEMM: M=8192 (64 blocks of TM=128), N=768 (6 n-blocks), MAP0
    gemm_bt<0,128,6,64,0,0><<<6*64, 256, 0, stream>>>(attn_o, Wobf, bo, d_out,
                                                      nullptr, nullptr, H, H);
}